// Round 4
// baseline (2486.158 us; speedup 1.0000x reference)
//
#include <hip/hip_runtime.h>
#include <hip/hip_bf16.h>
#include <math.h>

// Problem constants
#define B_  64
#define W_  128
#define L_  32
#define V_  128
#define E_  128
#define H_  256
#define G4_ 1024      // 4*H
#define NW  8192      // B*W words
#define KS_ 12        // MFMA k-steps: 8 for h (K=256) + 4 for one-hot chars (V=128)
#define KPAD 408      // padded LDS row (bf16): 384 used + 24 pad (816B = 51*16B, odd -> bank rotate)
#define M_  32        // words per block

typedef short s8v  __attribute__((ext_vector_type(8)));  // 8 bf16 (4 VGPR)
typedef float f4v  __attribute__((ext_vector_type(4)));

// ---------------------------------------------------------------------------
// K1: eproj[dir][v][g] = dot(emb[v], Wih_dir[g]) + bih[g] + bhh[g]   (fp32)
// ---------------------------------------------------------------------------
__global__ __launch_bounds__(256) void k_embproj(
    const float* __restrict__ emb,
    const float* __restrict__ Wih_f, const float* __restrict__ bih_f, const float* __restrict__ bhh_f,
    const float* __restrict__ Wih_b, const float* __restrict__ bih_b, const float* __restrict__ bhh_b,
    float* __restrict__ eproj) {
  int v   = blockIdx.x & (V_ - 1);
  int dir = blockIdx.x >> 7;
  const float* Wih = dir ? Wih_b : Wih_f;
  const float* b1  = dir ? bih_b : bih_f;
  const float* b2  = dir ? bhh_b : bhh_f;
  __shared__ float es[E_];
  if (threadIdx.x < E_) es[threadIdx.x] = emb[v * E_ + threadIdx.x];
  __syncthreads();
#pragma unroll
  for (int q = 0; q < 4; ++q) {
    int g = q * 256 + threadIdx.x;
    const float* wr = Wih + g * E_;
    float a = 0.f;
#pragma unroll 4
    for (int k = 0; k < E_; k += 4) {
      float4 w4 = *(const float4*)(wr + k);
      float4 e4 = *(const float4*)(es + k);
      a += w4.x * e4.x + w4.y * e4.y + w4.z * e4.z + w4.w * e4.w;
    }
    eproj[(dir * V_ + v) * G4_ + g] = a + b1[g] + b2[g];
  }
}

// ---------------------------------------------------------------------------
// K1b: pack B = [Whh^T ; eproj] (384 x 1024) per dir into MFMA B-fragment
// layout, bf16.  Element (ks, nt, lane, j) holds Bmat[k][n]:
//   k = ks*32 + (lane>>4)*8 + j,  n = nt*16 + (lane&15)
//   k <  256 : Whh[n][k]      (h recurrence)
//   k >= 256 : eproj[k-256][n] (one-hot char rows, biases folded in)
// ---------------------------------------------------------------------------
__global__ __launch_bounds__(64) void k_pack(
    const float* __restrict__ eproj,
    const float* __restrict__ Whh_f, const float* __restrict__ Whh_b,
    __hip_bfloat16* __restrict__ Bpack) {
  const int lane = threadIdx.x;
  const int nt   = blockIdx.x & 63;
  const int ks   = (blockIdx.x >> 6) % KS_;
  const int dir  = blockIdx.x / (64 * KS_);
  const float* Whh = dir ? Whh_b : Whh_f;
  const int n  = nt * 16 + (lane & 15);
  const int k0 = ks * 32 + (lane >> 4) * 8;
  size_t base = (((size_t)(dir * KS_ + ks) * 64 + nt) * 64 + lane) * 8;
#pragma unroll
  for (int j = 0; j < 8; ++j) {
    int k = k0 + j;
    float v = (k < H_) ? Whh[n * H_ + k]
                       : eproj[(dir * V_ + (k - H_)) * G4_ + n];
    Bpack[base + j] = __float2bfloat16(v);
  }
}

// ---------------------------------------------------------------------------
// K1c: deterministic stable counting sort of words by length, DESCENDING.
// One block, 256 threads = 8 chunks x 32 length-values. Longest words get
// the lowest perm slots -> LPT scheduling for k_lstm's variable-length blocks.
// ---------------------------------------------------------------------------
#define NCHUNK 8
#define CHSZ  (NW / NCHUNK)
__global__ __launch_bounds__(256) void k_sort(const int* __restrict__ word_lens,
                                              int* __restrict__ perm) {
  __shared__ int cnt_s[NCHUNK][33];
  __shared__ int off_s[NCHUNK][33];
  const int tid = threadIdx.x;
  const int ch  = tid >> 5;
  const int ln  = (tid & 31) + 1;   // 1..32
  const int base = ch * CHSZ;
  int c = 0;
  for (int i = 0; i < CHSZ; ++i) c += (word_lens[base + i] == ln);
  cnt_s[ch][ln] = c;
  __syncthreads();
  if (tid == 0) {
    int run = 0;
    for (int l = 32; l >= 1; --l)
      for (int c2 = 0; c2 < NCHUNK; ++c2) { off_s[c2][l] = run; run += cnt_s[c2][l]; }
  }
  __syncthreads();
  int ptr = off_s[ch][ln];
  for (int i = 0; i < CHSZ; ++i) {
    int wi = base + i;
    if (word_lens[wi] == ln) perm[ptr++] = wi;
  }
}

// ---------------------------------------------------------------------------
// K2: MFMA BiLSTM recurrence. Block = 32 sorted words x 1 dir, 8 waves.
// Wave w owns gate-columns x in {2w, 2w+1}: nt = u*16 + x  (u = gate 0..3).
// acc[u][jj][mt] (mt = word-tile 0..1) -> 64 f32/thread, fits 128 VGPR.
// A = [h | onehot(char)] bf16 in LDS.
// C/D layout (verified m89): word = mt*16 + (lane>>4)*4 + reg, col = lane&15.
// ---------------------------------------------------------------------------
__global__ __launch_bounds__(512, 4) void k_lstm(
    const int* __restrict__ char_ids, const int* __restrict__ word_lens,
    const int* __restrict__ perm,
    const __hip_bfloat16* __restrict__ Bpack, unsigned short* __restrict__ hcat) {
  const int tid  = threadIdx.x;
  const int lane = tid & 63;
  const int w    = tid >> 6;       // wave 0..7
  const int w0   = blockIdx.x * M_;
  const int dir  = blockIdx.y;     // 0 fwd, 1 bwd

  __shared__ unsigned short hL[M_][KPAD];  // 26 KB: [h 256 | onehot 128 | pad]
  __shared__ int ids_s[M_][L_];            // 4 KB
  __shared__ int len_s[M_];
  __shared__ int pw_s[M_];

  if (tid < M_) {
    int gw = perm[w0 + tid];
    pw_s[tid]  = gw;
    len_s[tid] = word_lens[gw];
  }
  __syncthreads();
  for (int i = tid; i < M_ * L_; i += 512) {
    int q = i >> 5;
    ids_s[q][i & 31] = char_ids[pw_s[q] * L_ + (i & 31)];
  }
  for (int i = tid; i < M_ * KPAD / 2; i += 512) ((unsigned int*)hL)[i] = 0u;
  __syncthreads();

  // one-hot for t=0
  if (tid < M_) {
    int len = len_s[tid];
    int tt  = dir ? (len - 1) : 0;
    hL[tid][H_ + ids_s[tid][tt]] = 0x3F80;  // bf16 1.0
  }
  int mlen = 0;
#pragma unroll 8
  for (int m = 0; m < M_; ++m) mlen = max(mlen, len_s[m]);
  // packed lens for this lane's 8 (mt, r) words: word = mt*16 + (lane>>4)*4 + r
  unsigned lrp[2];
#pragma unroll
  for (int mt = 0; mt < 2; ++mt) {
    int bw = mt * 16 + ((lane >> 4) << 2);
    lrp[mt] = (unsigned)len_s[bw] | ((unsigned)len_s[bw + 1] << 8) |
              ((unsigned)len_s[bw + 2] << 16) | ((unsigned)len_s[bw + 3] << 24);
  }
  __syncthreads();

  const char* Bb   = (const char*)(Bpack + (size_t)dir * (KS_ * 64 * 64 * 8));
  const int   aoff = (lane >> 4) << 4;     // byte offset of this lane's 8 k-elems
  const char* ar0  = (const char*)&hL[ 0 + (lane & 15)][0];
  const char* ar1  = (const char*)&hL[16 + (lane & 15)][0];

  float c_[2][2][4];                       // [jj][mt][r]
#pragma unroll
  for (int jj = 0; jj < 2; ++jj)
#pragma unroll
    for (int mt = 0; mt < 2; ++mt)
#pragma unroll
      for (int r = 0; r < 4; ++r) c_[jj][mt][r] = 0.f;

  for (int t = 0; t < mlen; ++t) {
    f4v acc[4][2][2];                      // [gate u][jj][mt]
#pragma unroll
    for (int u = 0; u < 4; ++u)
#pragma unroll
      for (int jj = 0; jj < 2; ++jj)
#pragma unroll
        for (int mt = 0; mt < 2; ++mt) acc[u][jj][mt] = (f4v){0.f, 0.f, 0.f, 0.f};

#pragma unroll
    for (int ks = 0; ks < KS_; ++ks) {
      s8v af0 = *(const s8v*)(ar0 + ks * 64 + aoff);
      s8v af1 = *(const s8v*)(ar1 + ks * 64 + aoff);
#pragma unroll
      for (int u = 0; u < 4; ++u) {
#pragma unroll
        for (int jj = 0; jj < 2; ++jj) {
          const int nt = u * 16 + 2 * w + jj;
          s8v bf = *(const s8v*)(Bb + (((size_t)ks * 64 + nt) * 64 + lane) * 16);
          acc[u][jj][0] = __builtin_amdgcn_mfma_f32_16x16x32_bf16(af0, bf, acc[u][jj][0], 0, 0, 0);
          acc[u][jj][1] = __builtin_amdgcn_mfma_f32_16x16x32_bf16(af1, bf, acc[u][jj][1], 0, 0, 0);
        }
      }
    }

    __syncthreads();   // all waves done reading hL for step t

    // elementwise gates + masked state update; write h_new (bf16) to LDS
#pragma unroll
    for (int jj = 0; jj < 2; ++jj) {
#pragma unroll
      for (int mt = 0; mt < 2; ++mt) {
#pragma unroll
        for (int r = 0; r < 4; ++r) {
          const int m = mt * 16 + ((lane >> 4) << 2) + r;
          const int p = (2 * w + jj) * 16 + (lane & 15);
          float gi = acc[0][jj][mt][r];
          float gf = acc[1][jj][mt][r];
          float gg = acc[2][jj][mt][r];
          float go = acc[3][jj][mt][r];
          float si = 1.f / (1.f + __expf(-gi));
          float sf = 1.f / (1.f + __expf(-gf));
          float so = 1.f / (1.f + __expf(-go));
          float tg = 2.f / (1.f + __expf(-2.f * gg)) - 1.f;
          float cn = sf * c_[jj][mt][r] + si * tg;
          float hn = so * (2.f / (1.f + __expf(-2.f * cn)) - 1.f);
          int len = (int)((lrp[mt] >> (8 * r)) & 255u);
          if (t < len) {
            c_[jj][mt][r] = cn;
            union { __hip_bfloat16 b; unsigned short u; } cv;
            cv.b = __float2bfloat16(hn);
            hL[m][p] = cv.u;
          }
        }
      }
    }
    // advance one-hot to step t+1
    if (tid < M_ && t + 1 < mlen) {
      int len  = len_s[tid];
      int told = dir ? max(len - 1 - t, 0)       : min(t, len - 1);
      int tnew = dir ? max(len - 1 - (t + 1), 0) : min(t + 1, len - 1);
      hL[tid][H_ + ids_s[tid][told]] = 0;
      hL[tid][H_ + ids_s[tid][tnew]] = 0x3F80;
    }
    __syncthreads();   // h(t+1) + one-hot(t+1) visible
  }

  // write frozen h (bf16) to hcat at ORIGINAL word position: [h_bwd | h_fwd]
  const int off = dir ? 0 : H_;
  for (int i = tid; i < M_ * H_; i += 512) {
    int q   = i >> 8;        // local word
    int pos = i & 255;
    hcat[(size_t)pw_s[q] * (2 * H_) + off + pos] = hL[q][pos];
  }
}

// ---------------------------------------------------------------------------
// K3: wemb = hcat(bf16) @ pW^T + pb;  also writes lens_out (= W) slots.
// ---------------------------------------------------------------------------
#define PM_ 16
__global__ __launch_bounds__(256) void k_proj(
    const unsigned short* __restrict__ hcat, const float* __restrict__ pW,
    const float* __restrict__ pb, float* __restrict__ out) {
  const int tid = threadIdx.x;
  const int n0  = blockIdx.x * PM_;
  __shared__ float hs[PM_][2 * H_];   // 32 KB
  for (int i = tid; i < PM_ * 2 * H_; i += 256) {
    unsigned int ui = ((unsigned int)hcat[(size_t)n0 * 2 * H_ + i]) << 16;
    ((float*)hs)[i] = __uint_as_float(ui);
  }
  __syncthreads();

  const float* pwr = pW + tid * (2 * H_);
  float acc[PM_];
#pragma unroll
  for (int m = 0; m < PM_; ++m) acc[m] = 0.f;

#pragma unroll 2
  for (int k = 0; k < 2 * H_; k += 4) {
    float4 w4 = *(const float4*)(pwr + k);
#pragma unroll
    for (int m = 0; m < PM_; ++m) {
      float4 h4 = *(const float4*)(&hs[m][k]);
      acc[m] += w4.x * h4.x + w4.y * h4.y + w4.z * h4.z + w4.w * h4.w;
    }
  }
  const float bias = pb[tid];
#pragma unroll
  for (int m = 0; m < PM_; ++m) out[(n0 + m) * H_ + tid] = acc[m] + bias;

  if (blockIdx.x == 0 && tid < B_) out[NW * H_ + tid] = (float)W_;
}

// ---------------------------------------------------------------------------
extern "C" void kernel_launch(void* const* d_in, const int* in_sizes, int n_in,
                              void* d_out, int out_size, void* d_ws, size_t ws_size,
                              hipStream_t stream) {
  const int*   char_ids  = (const int*)  d_in[0];
  const int*   word_lens = (const int*)  d_in[1];
  const float* emb       = (const float*)d_in[2];
  const float* Wih_f     = (const float*)d_in[3];
  const float* Whh_f     = (const float*)d_in[4];
  const float* bih_f     = (const float*)d_in[5];
  const float* bhh_f     = (const float*)d_in[6];
  const float* Wih_b     = (const float*)d_in[7];
  const float* Whh_b     = (const float*)d_in[8];
  const float* bih_b     = (const float*)d_in[9];
  const float* bhh_b     = (const float*)d_in[10];
  const float* pW        = (const float*)d_in[11];
  const float* pb        = (const float*)d_in[12];
  float* out = (float*)d_out;

  // ws layout: [Bpack 1.5MB][perm 32KB][eproj 1MB | hcat(bf16) 8.4MB]
  const size_t BPACK_BYTES = (size_t)2 * KS_ * 64 * 64 * 8 * 2;
  __hip_bfloat16* Bpack = (__hip_bfloat16*)d_ws;
  int*   perm  = (int*)((char*)d_ws + BPACK_BYTES);
  float* eproj = (float*)((char*)d_ws + BPACK_BYTES + NW * sizeof(int));
  unsigned short* hcat = (unsigned short*)eproj;  // eproj dead after k_pack

  k_embproj<<<dim3(2 * V_), dim3(256), 0, stream>>>(emb, Wih_f, bih_f, bhh_f,
                                                    Wih_b, bih_b, bhh_b, eproj);
  k_pack<<<dim3(2 * KS_ * 64), dim3(64), 0, stream>>>(eproj, Whh_f, Whh_b, Bpack);
  k_sort<<<dim3(1), dim3(256), 0, stream>>>(word_lens, perm);
  k_lstm<<<dim3(NW / M_, 2), dim3(512), 0, stream>>>(char_ids, word_lens, perm, Bpack, hcat);
  k_proj<<<dim3(NW / PM_), dim3(256), 0, stream>>>(hcat, pW, pb, out);
}

// Round 5
// 1661.003 us; speedup vs baseline: 1.4968x; 1.4968x over previous
//
#include <hip/hip_runtime.h>
#include <hip/hip_bf16.h>
#include <math.h>

// Problem constants
#define B_  64
#define W_  128
#define L_  32
#define V_  128
#define E_  128
#define H_  256
#define G4_ 1024      // 4*H
#define NW  8192      // B*W words
#define KS_ 12        // MFMA k-steps: 8 for h (K=256) + 4 for one-hot chars (V=128)
#define KPAD 408      // padded LDS row (bf16): 384 used + 24 pad
#define M_  64        // words per block

typedef short s8v  __attribute__((ext_vector_type(8)));  // 8 bf16 (4 VGPR)
typedef float f4v  __attribute__((ext_vector_type(4)));

// ---------------------------------------------------------------------------
// K1: eproj[dir][v][g] = dot(emb[v], Wih_dir[g]) + bih[g] + bhh[g]   (fp32)
// ---------------------------------------------------------------------------
__global__ __launch_bounds__(256) void k_embproj(
    const float* __restrict__ emb,
    const float* __restrict__ Wih_f, const float* __restrict__ bih_f, const float* __restrict__ bhh_f,
    const float* __restrict__ Wih_b, const float* __restrict__ bih_b, const float* __restrict__ bhh_b,
    float* __restrict__ eproj) {
  int v   = blockIdx.x & (V_ - 1);
  int dir = blockIdx.x >> 7;
  const float* Wih = dir ? Wih_b : Wih_f;
  const float* b1  = dir ? bih_b : bih_f;
  const float* b2  = dir ? bhh_b : bhh_f;
  __shared__ float es[E_];
  if (threadIdx.x < E_) es[threadIdx.x] = emb[v * E_ + threadIdx.x];
  __syncthreads();
#pragma unroll
  for (int q = 0; q < 4; ++q) {
    int g = q * 256 + threadIdx.x;
    const float* wr = Wih + g * E_;
    float a = 0.f;
#pragma unroll 4
    for (int k = 0; k < E_; k += 4) {
      float4 w4 = *(const float4*)(wr + k);
      float4 e4 = *(const float4*)(es + k);
      a += w4.x * e4.x + w4.y * e4.y + w4.z * e4.z + w4.w * e4.w;
    }
    eproj[(dir * V_ + v) * G4_ + g] = a + b1[g] + b2[g];
  }
}

// ---------------------------------------------------------------------------
// K1b: pack B = [Whh^T ; eproj] (384 x 1024) per dir into MFMA B-fragment
// layout, bf16.  Element (ks, nt, lane, j) holds Bmat[k][n]:
//   k = ks*32 + (lane>>4)*8 + j,  n = nt*16 + (lane&15)
//   k <  256 : Whh[n][k]      (h recurrence)
//   k >= 256 : eproj[k-256][n] (one-hot char rows, biases folded in)
// ---------------------------------------------------------------------------
__global__ __launch_bounds__(64) void k_pack(
    const float* __restrict__ eproj,
    const float* __restrict__ Whh_f, const float* __restrict__ Whh_b,
    __hip_bfloat16* __restrict__ Bpack) {
  const int lane = threadIdx.x;
  const int nt   = blockIdx.x & 63;
  const int ks   = (blockIdx.x >> 6) % KS_;
  const int dir  = blockIdx.x / (64 * KS_);
  const float* Whh = dir ? Whh_b : Whh_f;
  const int n  = nt * 16 + (lane & 15);
  const int k0 = ks * 32 + (lane >> 4) * 8;
  size_t base = (((size_t)(dir * KS_ + ks) * 64 + nt) * 64 + lane) * 8;
#pragma unroll
  for (int j = 0; j < 8; ++j) {
    int k = k0 + j;
    float v = (k < H_) ? Whh[n * H_ + k]
                       : eproj[(dir * V_ + (k - H_)) * G4_ + n];
    Bpack[base + j] = __float2bfloat16(v);
  }
}

// ---------------------------------------------------------------------------
// K1c: deterministic stable counting sort of words by length, DESCENDING.
// Longest words get the lowest perm slots -> length-uniform blocks (small
// mlen) and LPT dispatch order for k_lstm.
// ---------------------------------------------------------------------------
#define NCHUNK 8
#define CHSZ  (NW / NCHUNK)
__global__ __launch_bounds__(256) void k_sort(const int* __restrict__ word_lens,
                                              int* __restrict__ perm) {
  __shared__ int cnt_s[NCHUNK][33];
  __shared__ int off_s[NCHUNK][33];
  const int tid = threadIdx.x;
  const int ch  = tid >> 5;
  const int ln  = (tid & 31) + 1;   // 1..32
  const int base = ch * CHSZ;
  int c = 0;
  for (int i = 0; i < CHSZ; ++i) c += (word_lens[base + i] == ln);
  cnt_s[ch][ln] = c;
  __syncthreads();
  if (tid == 0) {
    int run = 0;
    for (int l = 32; l >= 1; --l)
      for (int c2 = 0; c2 < NCHUNK; ++c2) { off_s[c2][l] = run; run += cnt_s[c2][l]; }
  }
  __syncthreads();
  int ptr = off_s[ch][ln];
  for (int i = 0; i < CHSZ; ++i) {
    int wi = base + i;
    if (word_lens[wi] == ln) perm[ptr++] = wi;
  }
}

// ---------------------------------------------------------------------------
// K2: MFMA BiLSTM recurrence. Block = 64 sorted words x 1 dir, 8 waves.
// Wave w owns gate-columns x in {2w, 2w+1}: nt = u*16 + x  (u = gate 0..3).
// acc[u][jj][mt] (mt = word-tile 0..3): 128 f32/thread -> AGPRs; total live
// ~220 regs, under the 256 cap from __launch_bounds__(512,1) (empirical:
// 2nd arg behaves as blocks/CU on this toolchain: (512,2)->128, (512,4)->64).
// A = [h | onehot(char)] bf16 in LDS.
// C/D layout (verified m89): word = mt*16 + (lane>>4)*4 + reg, col = lane&15.
// ---------------------------------------------------------------------------
__global__ __launch_bounds__(512, 1) void k_lstm(
    const int* __restrict__ char_ids, const int* __restrict__ word_lens,
    const int* __restrict__ perm,
    const __hip_bfloat16* __restrict__ Bpack, unsigned short* __restrict__ hcat) {
  const int tid  = threadIdx.x;
  const int lane = tid & 63;
  const int w    = tid >> 6;       // wave 0..7
  const int w0   = blockIdx.x * M_;
  const int dir  = blockIdx.y;     // 0 fwd, 1 bwd

  __shared__ unsigned short hL[M_][KPAD];  // 52 KB: [h 256 | onehot 128 | pad]
  __shared__ int ids_s[M_][L_];            // 8 KB
  __shared__ int len_s[M_];
  __shared__ int pw_s[M_];

  if (tid < M_) {
    int gw = perm[w0 + tid];
    pw_s[tid]  = gw;
    len_s[tid] = word_lens[gw];
  }
  __syncthreads();
  for (int i = tid; i < M_ * L_; i += 512) {
    int q = i >> 5;
    ids_s[q][i & 31] = char_ids[pw_s[q] * L_ + (i & 31)];
  }
  for (int i = tid; i < M_ * KPAD / 2; i += 512) ((unsigned int*)hL)[i] = 0u;
  __syncthreads();

  // one-hot for t=0
  if (tid < M_) {
    int len = len_s[tid];
    int tt  = dir ? (len - 1) : 0;
    hL[tid][H_ + ids_s[tid][tt]] = 0x3F80;  // bf16 1.0
  }
  int mlen = 0;
#pragma unroll 8
  for (int m = 0; m < M_; ++m) mlen = max(mlen, len_s[m]);
  // packed lens for this lane's 16 (mt, r) words: word = mt*16 + (lane>>4)*4 + r
  unsigned lrp[4];
#pragma unroll
  for (int mt = 0; mt < 4; ++mt) {
    int bw = mt * 16 + ((lane >> 4) << 2);
    lrp[mt] = (unsigned)len_s[bw] | ((unsigned)len_s[bw + 1] << 8) |
              ((unsigned)len_s[bw + 2] << 16) | ((unsigned)len_s[bw + 3] << 24);
  }
  __syncthreads();

  const char* Bb   = (const char*)(Bpack + (size_t)dir * (KS_ * 64 * 64 * 8));
  const int   aoff = (lane >> 4) << 4;     // byte offset of this lane's 8 k-elems
  const char* ar0  = (const char*)&hL[ 0 + (lane & 15)][0];
  const char* ar1  = (const char*)&hL[16 + (lane & 15)][0];
  const char* ar2  = (const char*)&hL[32 + (lane & 15)][0];
  const char* ar3  = (const char*)&hL[48 + (lane & 15)][0];

  float c_[2][4][4];                       // [jj][mt][r]
#pragma unroll
  for (int jj = 0; jj < 2; ++jj)
#pragma unroll
    for (int mt = 0; mt < 4; ++mt)
#pragma unroll
      for (int r = 0; r < 4; ++r) c_[jj][mt][r] = 0.f;

  for (int t = 0; t < mlen; ++t) {
    f4v acc[4][2][4];                      // [gate u][jj][mt]
#pragma unroll
    for (int u = 0; u < 4; ++u)
#pragma unroll
      for (int jj = 0; jj < 2; ++jj)
#pragma unroll
        for (int mt = 0; mt < 4; ++mt) acc[u][jj][mt] = (f4v){0.f, 0.f, 0.f, 0.f};

#pragma unroll
    for (int ks = 0; ks < KS_; ++ks) {
      s8v af0 = *(const s8v*)(ar0 + ks * 64 + aoff);
      s8v af1 = *(const s8v*)(ar1 + ks * 64 + aoff);
      s8v af2 = *(const s8v*)(ar2 + ks * 64 + aoff);
      s8v af3 = *(const s8v*)(ar3 + ks * 64 + aoff);
#pragma unroll
      for (int u = 0; u < 4; ++u) {
#pragma unroll
        for (int jj = 0; jj < 2; ++jj) {
          const int nt = u * 16 + 2 * w + jj;
          s8v bf = *(const s8v*)(Bb + (((size_t)ks * 64 + nt) * 64 + lane) * 16);
          acc[u][jj][0] = __builtin_amdgcn_mfma_f32_16x16x32_bf16(af0, bf, acc[u][jj][0], 0, 0, 0);
          acc[u][jj][1] = __builtin_amdgcn_mfma_f32_16x16x32_bf16(af1, bf, acc[u][jj][1], 0, 0, 0);
          acc[u][jj][2] = __builtin_amdgcn_mfma_f32_16x16x32_bf16(af2, bf, acc[u][jj][2], 0, 0, 0);
          acc[u][jj][3] = __builtin_amdgcn_mfma_f32_16x16x32_bf16(af3, bf, acc[u][jj][3], 0, 0, 0);
        }
      }
    }

    __syncthreads();   // all waves done reading hL for step t

    // elementwise gates + masked state update; write h_new (bf16) to LDS
#pragma unroll
    for (int jj = 0; jj < 2; ++jj) {
#pragma unroll
      for (int mt = 0; mt < 4; ++mt) {
#pragma unroll
        for (int r = 0; r < 4; ++r) {
          const int m = mt * 16 + ((lane >> 4) << 2) + r;
          const int p = (2 * w + jj) * 16 + (lane & 15);
          float gi = acc[0][jj][mt][r];
          float gf = acc[1][jj][mt][r];
          float gg = acc[2][jj][mt][r];
          float go = acc[3][jj][mt][r];
          float si = 1.f / (1.f + __expf(-gi));
          float sf = 1.f / (1.f + __expf(-gf));
          float so = 1.f / (1.f + __expf(-go));
          float tg = 2.f / (1.f + __expf(-2.f * gg)) - 1.f;
          float cn = sf * c_[jj][mt][r] + si * tg;
          float hn = so * (2.f / (1.f + __expf(-2.f * cn)) - 1.f);
          int len = (int)((lrp[mt] >> (8 * r)) & 255u);
          if (t < len) {
            c_[jj][mt][r] = cn;
            union { __hip_bfloat16 b; unsigned short u; } cv;
            cv.b = __float2bfloat16(hn);
            hL[m][p] = cv.u;
          }
        }
      }
    }
    // advance one-hot to step t+1
    if (tid < M_ && t + 1 < mlen) {
      int len  = len_s[tid];
      int told = dir ? max(len - 1 - t, 0)       : min(t, len - 1);
      int tnew = dir ? max(len - 1 - (t + 1), 0) : min(t + 1, len - 1);
      hL[tid][H_ + ids_s[tid][told]] = 0;
      hL[tid][H_ + ids_s[tid][tnew]] = 0x3F80;
    }
    __syncthreads();   // h(t+1) + one-hot(t+1) visible
  }

  // write frozen h (bf16) to hcat at ORIGINAL word position: [h_bwd | h_fwd]
  const int off = dir ? 0 : H_;
  for (int i = tid; i < M_ * H_; i += 512) {
    int q   = i >> 8;        // local word
    int pos = i & 255;
    hcat[(size_t)pw_s[q] * (2 * H_) + off + pos] = hL[q][pos];
  }
}

// ---------------------------------------------------------------------------
// K3: wemb = hcat(bf16) @ pW^T + pb;  also writes lens_out (= W) slots.
// ---------------------------------------------------------------------------
#define PM_ 16
__global__ __launch_bounds__(256) void k_proj(
    const unsigned short* __restrict__ hcat, const float* __restrict__ pW,
    const float* __restrict__ pb, float* __restrict__ out) {
  const int tid = threadIdx.x;
  const int n0  = blockIdx.x * PM_;
  __shared__ float hs[PM_][2 * H_];   // 32 KB
  for (int i = tid; i < PM_ * 2 * H_; i += 256) {
    unsigned int ui = ((unsigned int)hcat[(size_t)n0 * 2 * H_ + i]) << 16;
    ((float*)hs)[i] = __uint_as_float(ui);
  }
  __syncthreads();

  const float* pwr = pW + tid * (2 * H_);
  float acc[PM_];
#pragma unroll
  for (int m = 0; m < PM_; ++m) acc[m] = 0.f;

#pragma unroll 2
  for (int k = 0; k < 2 * H_; k += 4) {
    float4 w4 = *(const float4*)(pwr + k);
#pragma unroll
    for (int m = 0; m < PM_; ++m) {
      float4 h4 = *(const float4*)(&hs[m][k]);
      acc[m] += w4.x * h4.x + w4.y * h4.y + w4.z * h4.z + w4.w * h4.w;
    }
  }
  const float bias = pb[tid];
#pragma unroll
  for (int m = 0; m < PM_; ++m) out[(n0 + m) * H_ + tid] = acc[m] + bias;

  if (blockIdx.x == 0 && tid < B_) out[NW * H_ + tid] = (float)W_;
}

// ---------------------------------------------------------------------------
extern "C" void kernel_launch(void* const* d_in, const int* in_sizes, int n_in,
                              void* d_out, int out_size, void* d_ws, size_t ws_size,
                              hipStream_t stream) {
  const int*   char_ids  = (const int*)  d_in[0];
  const int*   word_lens = (const int*)  d_in[1];
  const float* emb       = (const float*)d_in[2];
  const float* Wih_f     = (const float*)d_in[3];
  const float* Whh_f     = (const float*)d_in[4];
  const float* bih_f     = (const float*)d_in[5];
  const float* bhh_f     = (const float*)d_in[6];
  const float* Wih_b     = (const float*)d_in[7];
  const float* Whh_b     = (const float*)d_in[8];
  const float* bih_b     = (const float*)d_in[9];
  const float* bhh_b     = (const float*)d_in[10];
  const float* pW        = (const float*)d_in[11];
  const float* pb        = (const float*)d_in[12];
  float* out = (float*)d_out;

  // ws layout: [Bpack 1.5MB][perm 32KB][eproj 1MB | hcat(bf16) 8.4MB]
  const size_t BPACK_BYTES = (size_t)2 * KS_ * 64 * 64 * 8 * 2;
  __hip_bfloat16* Bpack = (__hip_bfloat16*)d_ws;
  int*   perm  = (int*)((char*)d_ws + BPACK_BYTES);
  float* eproj = (float*)((char*)d_ws + BPACK_BYTES + NW * sizeof(int));
  unsigned short* hcat = (unsigned short*)eproj;  // eproj dead after k_pack

  k_sort<<<dim3(1), dim3(256), 0, stream>>>(word_lens, perm);
  k_embproj<<<dim3(2 * V_), dim3(256), 0, stream>>>(emb, Wih_f, bih_f, bhh_f,
                                                    Wih_b, bih_b, bhh_b, eproj);
  k_pack<<<dim3(2 * KS_ * 64), dim3(64), 0, stream>>>(eproj, Whh_f, Whh_b, Bpack);
  k_lstm<<<dim3(NW / M_, 2), dim3(512), 0, stream>>>(char_ids, word_lens, perm, Bpack, hcat);
  k_proj<<<dim3(NW / PM_), dim3(256), 0, stream>>>(hcat, pW, pb, out);
}

// Round 6
// 1197.713 us; speedup vs baseline: 2.0758x; 1.3868x over previous
//
#include <hip/hip_runtime.h>
#include <hip/hip_bf16.h>
#include <math.h>

// Problem constants
#define B_  64
#define W_  128
#define L_  32
#define V_  128
#define E_  128
#define H_  256
#define G4_ 1024      // 4*H
#define NW  8192      // B*W words
#define KS_ 12        // MFMA k-steps: 8 for h (K=256) + 4 for one-hot chars (V=128)
#define KPAD 392      // padded LDS row (bf16): 384 used + 8 pad (784B = 49*16B, odd -> quad spread)
#define M_  32        // words per block

typedef short s8v  __attribute__((ext_vector_type(8)));  // 8 bf16 (4 VGPR)
typedef float f4v  __attribute__((ext_vector_type(4)));

// ---------------------------------------------------------------------------
// K1: eproj[dir][v][g] = dot(emb[v], Wih_dir[g]) + bih[g] + bhh[g]   (fp32)
// ---------------------------------------------------------------------------
__global__ __launch_bounds__(256) void k_embproj(
    const float* __restrict__ emb,
    const float* __restrict__ Wih_f, const float* __restrict__ bih_f, const float* __restrict__ bhh_f,
    const float* __restrict__ Wih_b, const float* __restrict__ bih_b, const float* __restrict__ bhh_b,
    float* __restrict__ eproj) {
  int v   = blockIdx.x & (V_ - 1);
  int dir = blockIdx.x >> 7;
  const float* Wih = dir ? Wih_b : Wih_f;
  const float* b1  = dir ? bih_b : bih_f;
  const float* b2  = dir ? bhh_b : bhh_f;
  __shared__ float es[E_];
  if (threadIdx.x < E_) es[threadIdx.x] = emb[v * E_ + threadIdx.x];
  __syncthreads();
#pragma unroll
  for (int q = 0; q < 4; ++q) {
    int g = q * 256 + threadIdx.x;
    const float* wr = Wih + g * E_;
    float a = 0.f;
#pragma unroll 4
    for (int k = 0; k < E_; k += 4) {
      float4 w4 = *(const float4*)(wr + k);
      float4 e4 = *(const float4*)(es + k);
      a += w4.x * e4.x + w4.y * e4.y + w4.z * e4.z + w4.w * e4.w;
    }
    eproj[(dir * V_ + v) * G4_ + g] = a + b1[g] + b2[g];
  }
}

// ---------------------------------------------------------------------------
// K1b: pack B = [Whh^T ; eproj] (384 x 1024) per dir into MFMA B-fragment
// layout, bf16.  Element (ks, nt, lane, j) holds Bmat[k][n]:
//   k = ks*32 + (lane>>4)*8 + j,  n = nt*16 + (lane&15)
//   k <  256 : Whh[n][k]      (h recurrence)
//   k >= 256 : eproj[k-256][n] (one-hot char rows, biases folded in)
// ---------------------------------------------------------------------------
__global__ __launch_bounds__(64) void k_pack(
    const float* __restrict__ eproj,
    const float* __restrict__ Whh_f, const float* __restrict__ Whh_b,
    __hip_bfloat16* __restrict__ Bpack) {
  const int lane = threadIdx.x;
  const int nt   = blockIdx.x & 63;
  const int ks   = (blockIdx.x >> 6) % KS_;
  const int dir  = blockIdx.x / (64 * KS_);
  const float* Whh = dir ? Whh_b : Whh_f;
  const int n  = nt * 16 + (lane & 15);
  const int k0 = ks * 32 + (lane >> 4) * 8;
  size_t base = (((size_t)(dir * KS_ + ks) * 64 + nt) * 64 + lane) * 8;
#pragma unroll
  for (int j = 0; j < 8; ++j) {
    int k = k0 + j;
    float v = (k < H_) ? Whh[n * H_ + k]
                       : eproj[(dir * V_ + (k - H_)) * G4_ + n];
    Bpack[base + j] = __float2bfloat16(v);
  }
}

// ---------------------------------------------------------------------------
// K1c: deterministic stable counting sort of words by length, DESCENDING.
// Longest words get the lowest perm slots -> length-uniform blocks (small
// mlen) and LPT dispatch order for k_lstm.
// ---------------------------------------------------------------------------
#define NCHUNK 8
#define CHSZ  (NW / NCHUNK)
__global__ __launch_bounds__(256) void k_sort(const int* __restrict__ word_lens,
                                              int* __restrict__ perm) {
  __shared__ int cnt_s[NCHUNK][33];
  __shared__ int off_s[NCHUNK][33];
  const int tid = threadIdx.x;
  const int ch  = tid >> 5;
  const int ln  = (tid & 31) + 1;   // 1..32
  const int base = ch * CHSZ;
  int c = 0;
  for (int i = 0; i < CHSZ; ++i) c += (word_lens[base + i] == ln);
  cnt_s[ch][ln] = c;
  __syncthreads();
  if (tid == 0) {
    int run = 0;
    for (int l = 32; l >= 1; --l)
      for (int c2 = 0; c2 < NCHUNK; ++c2) { off_s[c2][l] = run; run += cnt_s[c2][l]; }
  }
  __syncthreads();
  int ptr = off_s[ch][ln];
  for (int i = 0; i < CHSZ; ++i) {
    int wi = base + i;
    if (word_lens[wi] == ln) perm[ptr++] = wi;
  }
}

// ---------------------------------------------------------------------------
// K2: MFMA BiLSTM recurrence. Block = 32 sorted words x 1 dir, 8 waves.
// Wave w owns gate-columns x in {2w, 2w+1}: nt = u*16 + x  (u = gate 0..3).
// acc[u][jj][mt] (mt = word-tile 0..1) = 64 f32/thread; worst-case all-VGPR
// live set ~118 regs <= the 128 cap from __launch_bounds__(512,2) -> NO SPILL
// (rounds 3-5 showed spill traffic dominating when acc tile was 128/thread).
// A = [h | onehot(char)] bf16 in LDS.
// C/D layout (verified m89): word = mt*16 + (lane>>4)*4 + reg, col = lane&15.
// ---------------------------------------------------------------------------
__global__ __launch_bounds__(512, 2) void k_lstm(
    const int* __restrict__ char_ids, const int* __restrict__ word_lens,
    const int* __restrict__ perm,
    const __hip_bfloat16* __restrict__ Bpack, unsigned short* __restrict__ hcat) {
  const int tid  = threadIdx.x;
  const int lane = tid & 63;
  const int w    = tid >> 6;       // wave 0..7
  const int w0   = blockIdx.x * M_;
  const int dir  = blockIdx.y;     // 0 fwd, 1 bwd

  __shared__ unsigned short hL[M_][KPAD];  // 24.5 KB: [h 256 | onehot 128 | pad]
  __shared__ int ids_s[M_][L_];            // 4 KB
  __shared__ int len_s[M_];
  __shared__ int pw_s[M_];

  if (tid < M_) {
    int gw = perm[w0 + tid];
    pw_s[tid]  = gw;
    len_s[tid] = word_lens[gw];
  }
  __syncthreads();
  for (int i = tid; i < M_ * L_; i += 512) {
    int q = i >> 5;
    ids_s[q][i & 31] = char_ids[pw_s[q] * L_ + (i & 31)];
  }
  for (int i = tid; i < M_ * KPAD / 2; i += 512) ((unsigned int*)hL)[i] = 0u;
  __syncthreads();

  // one-hot for t=0
  if (tid < M_) {
    int len = len_s[tid];
    int tt  = dir ? (len - 1) : 0;
    hL[tid][H_ + ids_s[tid][tt]] = 0x3F80;  // bf16 1.0
  }
  int mlen = 0;
#pragma unroll 8
  for (int m = 0; m < M_; ++m) mlen = max(mlen, len_s[m]);
  // packed lens for this lane's 8 (mt, r) words: word = mt*16 + (lane>>4)*4 + r
  unsigned lrp[2];
#pragma unroll
  for (int mt = 0; mt < 2; ++mt) {
    int bw = mt * 16 + ((lane >> 4) << 2);
    lrp[mt] = (unsigned)len_s[bw] | ((unsigned)len_s[bw + 1] << 8) |
              ((unsigned)len_s[bw + 2] << 16) | ((unsigned)len_s[bw + 3] << 24);
  }
  __syncthreads();

  const char* Bb   = (const char*)(Bpack + (size_t)dir * (KS_ * 64 * 64 * 8));
  const int   aoff = (lane >> 4) << 4;     // byte offset of this lane's 8 k-elems
  const char* ar0  = (const char*)&hL[ 0 + (lane & 15)][0];
  const char* ar1  = (const char*)&hL[16 + (lane & 15)][0];

  float c_[2][2][4];                       // [jj][mt][r]
#pragma unroll
  for (int jj = 0; jj < 2; ++jj)
#pragma unroll
    for (int mt = 0; mt < 2; ++mt)
#pragma unroll
      for (int r = 0; r < 4; ++r) c_[jj][mt][r] = 0.f;

  for (int t = 0; t < mlen; ++t) {
    f4v acc[4][2][2];                      // [gate u][jj][mt]
#pragma unroll
    for (int u = 0; u < 4; ++u)
#pragma unroll
      for (int jj = 0; jj < 2; ++jj)
#pragma unroll
        for (int mt = 0; mt < 2; ++mt) acc[u][jj][mt] = (f4v){0.f, 0.f, 0.f, 0.f};

#pragma unroll
    for (int ks = 0; ks < KS_; ++ks) {
      s8v af0 = *(const s8v*)(ar0 + ks * 64 + aoff);
      s8v af1 = *(const s8v*)(ar1 + ks * 64 + aoff);
#pragma unroll
      for (int u = 0; u < 4; ++u) {
#pragma unroll
        for (int jj = 0; jj < 2; ++jj) {
          const int nt = u * 16 + 2 * w + jj;
          s8v bf = *(const s8v*)(Bb + (((size_t)ks * 64 + nt) * 64 + lane) * 16);
          acc[u][jj][0] = __builtin_amdgcn_mfma_f32_16x16x32_bf16(af0, bf, acc[u][jj][0], 0, 0, 0);
          acc[u][jj][1] = __builtin_amdgcn_mfma_f32_16x16x32_bf16(af1, bf, acc[u][jj][1], 0, 0, 0);
        }
      }
    }

    __syncthreads();   // all waves done reading hL for step t

    // elementwise gates + masked state update; write h_new (bf16) to LDS
#pragma unroll
    for (int jj = 0; jj < 2; ++jj) {
#pragma unroll
      for (int mt = 0; mt < 2; ++mt) {
#pragma unroll
        for (int r = 0; r < 4; ++r) {
          const int m = mt * 16 + ((lane >> 4) << 2) + r;
          const int p = (2 * w + jj) * 16 + (lane & 15);
          float gi = acc[0][jj][mt][r];
          float gf = acc[1][jj][mt][r];
          float gg = acc[2][jj][mt][r];
          float go = acc[3][jj][mt][r];
          float si = 1.f / (1.f + __expf(-gi));
          float sf = 1.f / (1.f + __expf(-gf));
          float so = 1.f / (1.f + __expf(-go));
          float tg = 2.f / (1.f + __expf(-2.f * gg)) - 1.f;
          float cn = sf * c_[jj][mt][r] + si * tg;
          float hn = so * (2.f / (1.f + __expf(-2.f * cn)) - 1.f);
          int len = (int)((lrp[mt] >> (8 * r)) & 255u);
          if (t < len) {
            c_[jj][mt][r] = cn;
            union { __hip_bfloat16 b; unsigned short u; } cv;
            cv.b = __float2bfloat16(hn);
            hL[m][p] = cv.u;
          }
        }
      }
    }
    // advance one-hot to step t+1
    if (tid < M_ && t + 1 < mlen) {
      int len  = len_s[tid];
      int told = dir ? max(len - 1 - t, 0)       : min(t, len - 1);
      int tnew = dir ? max(len - 1 - (t + 1), 0) : min(t + 1, len - 1);
      hL[tid][H_ + ids_s[tid][told]] = 0;
      hL[tid][H_ + ids_s[tid][tnew]] = 0x3F80;
    }
    __syncthreads();   // h(t+1) + one-hot(t+1) visible
  }

  // write frozen h (bf16) to hcat at ORIGINAL word position: [h_bwd | h_fwd]
  const int off = dir ? 0 : H_;
  for (int i = tid; i < M_ * H_; i += 512) {
    int q   = i >> 8;        // local word
    int pos = i & 255;
    hcat[(size_t)pw_s[q] * (2 * H_) + off + pos] = hL[q][pos];
  }
}

// ---------------------------------------------------------------------------
// K3: wemb = hcat(bf16) @ pW^T + pb;  also writes lens_out (= W) slots.
// ---------------------------------------------------------------------------
#define PM_ 16
__global__ __launch_bounds__(256) void k_proj(
    const unsigned short* __restrict__ hcat, const float* __restrict__ pW,
    const float* __restrict__ pb, float* __restrict__ out) {
  const int tid = threadIdx.x;
  const int n0  = blockIdx.x * PM_;
  __shared__ float hs[PM_][2 * H_];   // 32 KB
  for (int i = tid; i < PM_ * 2 * H_; i += 256) {
    unsigned int ui = ((unsigned int)hcat[(size_t)n0 * 2 * H_ + i]) << 16;
    ((float*)hs)[i] = __uint_as_float(ui);
  }
  __syncthreads();

  const float* pwr = pW + tid * (2 * H_);
  float acc[PM_];
#pragma unroll
  for (int m = 0; m < PM_; ++m) acc[m] = 0.f;

#pragma unroll 2
  for (int k = 0; k < 2 * H_; k += 4) {
    float4 w4 = *(const float4*)(pwr + k);
#pragma unroll
    for (int m = 0; m < PM_; ++m) {
      float4 h4 = *(const float4*)(&hs[m][k]);
      acc[m] += w4.x * h4.x + w4.y * h4.y + w4.z * h4.z + w4.w * h4.w;
    }
  }
  const float bias = pb[tid];
#pragma unroll
  for (int m = 0; m < PM_; ++m) out[(n0 + m) * H_ + tid] = acc[m] + bias;

  if (blockIdx.x == 0 && tid < B_) out[NW * H_ + tid] = (float)W_;
}

// ---------------------------------------------------------------------------
extern "C" void kernel_launch(void* const* d_in, const int* in_sizes, int n_in,
                              void* d_out, int out_size, void* d_ws, size_t ws_size,
                              hipStream_t stream) {
  const int*   char_ids  = (const int*)  d_in[0];
  const int*   word_lens = (const int*)  d_in[1];
  const float* emb       = (const float*)d_in[2];
  const float* Wih_f     = (const float*)d_in[3];
  const float* Whh_f     = (const float*)d_in[4];
  const float* bih_f     = (const float*)d_in[5];
  const float* bhh_f     = (const float*)d_in[6];
  const float* Wih_b     = (const float*)d_in[7];
  const float* Whh_b     = (const float*)d_in[8];
  const float* bih_b     = (const float*)d_in[9];
  const float* bhh_b     = (const float*)d_in[10];
  const float* pW        = (const float*)d_in[11];
  const float* pb        = (const float*)d_in[12];
  float* out = (float*)d_out;

  // ws layout: [Bpack 1.5MB][perm 32KB][eproj 1MB | hcat(bf16) 8.4MB]
  const size_t BPACK_BYTES = (size_t)2 * KS_ * 64 * 64 * 8 * 2;
  __hip_bfloat16* Bpack = (__hip_bfloat16*)d_ws;
  int*   perm  = (int*)((char*)d_ws + BPACK_BYTES);
  float* eproj = (float*)((char*)d_ws + BPACK_BYTES + NW * sizeof(int));
  unsigned short* hcat = (unsigned short*)eproj;  // eproj dead after k_pack

  k_sort<<<dim3(1), dim3(256), 0, stream>>>(word_lens, perm);
  k_embproj<<<dim3(2 * V_), dim3(256), 0, stream>>>(emb, Wih_f, bih_f, bhh_f,
                                                    Wih_b, bih_b, bhh_b, eproj);
  k_pack<<<dim3(2 * KS_ * 64), dim3(64), 0, stream>>>(eproj, Whh_f, Whh_b, Bpack);
  k_lstm<<<dim3(NW / M_, 2), dim3(512), 0, stream>>>(char_ids, word_lens, perm, Bpack, hcat);
  k_proj<<<dim3(NW / PM_), dim3(256), 0, stream>>>(hcat, pW, pb, out);
}

// Round 7
// 834.940 us; speedup vs baseline: 2.9777x; 1.4345x over previous
//
#include <hip/hip_runtime.h>
#include <hip/hip_bf16.h>
#include <math.h>

// Problem constants
#define B_  64
#define W_  128
#define L_  32
#define V_  128
#define E_  128
#define H_  256
#define G4_ 1024      // 4*H
#define NW  8192      // B*W words
#define KS_ 12        // MFMA k-steps: 8 for h (K=256) + 4 for one-hot chars (V=128)
#define KPAD 392      // padded LDS row (bf16): 384 used + 8 pad (784B = 49*16B, odd)
#define M_  32        // words per block

typedef short s8v  __attribute__((ext_vector_type(8)));  // 8 bf16 (4 VGPR)
typedef float f4v  __attribute__((ext_vector_type(4)));

// ---------------------------------------------------------------------------
// K1: eproj[dir][v][g] = dot(emb[v], Wih_dir[g]) + bih[g] + bhh[g]   (fp32)
// ---------------------------------------------------------------------------
__global__ __launch_bounds__(256) void k_embproj(
    const float* __restrict__ emb,
    const float* __restrict__ Wih_f, const float* __restrict__ bih_f, const float* __restrict__ bhh_f,
    const float* __restrict__ Wih_b, const float* __restrict__ bih_b, const float* __restrict__ bhh_b,
    float* __restrict__ eproj) {
  int v   = blockIdx.x & (V_ - 1);
  int dir = blockIdx.x >> 7;
  const float* Wih = dir ? Wih_b : Wih_f;
  const float* b1  = dir ? bih_b : bih_f;
  const float* b2  = dir ? bhh_b : bhh_f;
  __shared__ float es[E_];
  if (threadIdx.x < E_) es[threadIdx.x] = emb[v * E_ + threadIdx.x];
  __syncthreads();
#pragma unroll
  for (int q = 0; q < 4; ++q) {
    int g = q * 256 + threadIdx.x;
    const float* wr = Wih + g * E_;
    float a = 0.f;
#pragma unroll 4
    for (int k = 0; k < E_; k += 4) {
      float4 w4 = *(const float4*)(wr + k);
      float4 e4 = *(const float4*)(es + k);
      a += w4.x * e4.x + w4.y * e4.y + w4.z * e4.z + w4.w * e4.w;
    }
    eproj[(dir * V_ + v) * G4_ + g] = a + b1[g] + b2[g];
  }
}

// ---------------------------------------------------------------------------
// K1b: pack B = [Whh^T ; eproj] (384 x 1024) per dir into per-WAVE-contiguous
// MFMA B-fragment layout:  Bpack[dir][ks][w][f][lane][8 elems]  (bf16)
//   f = u*2 + jj (u = gate 0..3, jj = column pair) -> nt = u*16 + 2*w + jj
//   element j of (lane): Bmat[k][n], k = ks*32 + (lane>>4)*8 + j,
//                                    n = nt*16 + (lane&15)
//   k <  256 : Whh[n][k]       (h recurrence)
//   k >= 256 : eproj[k-256][n] (one-hot char rows, biases folded in)
// Per (ks,w) a wave's 8 fragments are one contiguous 8KB chunk -> the hot
// loop needs only 2 base pointers + immediate offsets (no address spill).
// ---------------------------------------------------------------------------
__global__ __launch_bounds__(64) void k_pack(
    const float* __restrict__ eproj,
    const float* __restrict__ Whh_f, const float* __restrict__ Whh_b,
    __hip_bfloat16* __restrict__ Bpack) {
  const int lane = threadIdx.x;
  const int f    = blockIdx.x & 7;
  const int w    = (blockIdx.x >> 3) & 7;
  const int ks   = (blockIdx.x >> 6) % KS_;
  const int dir  = blockIdx.x / (64 * KS_);
  const float* Whh = dir ? Whh_b : Whh_f;
  const int u  = f >> 1, jj = f & 1;
  const int nt = u * 16 + 2 * w + jj;
  const int n  = nt * 16 + (lane & 15);
  const int k0 = ks * 32 + (lane >> 4) * 8;
  size_t base = ((((size_t)(dir * KS_ + ks) * 8 + w) * 8 + f) * 64 + lane) * 8;
#pragma unroll
  for (int j = 0; j < 8; ++j) {
    int k = k0 + j;
    float v = (k < H_) ? Whh[n * H_ + k]
                       : eproj[(dir * V_ + (k - H_)) * G4_ + n];
    Bpack[base + j] = __float2bfloat16(v);
  }
}

// ---------------------------------------------------------------------------
// K1c: deterministic stable counting sort of words by length, DESCENDING.
// ---------------------------------------------------------------------------
#define NCHUNK 8
#define CHSZ  (NW / NCHUNK)
__global__ __launch_bounds__(256) void k_sort(const int* __restrict__ word_lens,
                                              int* __restrict__ perm) {
  __shared__ int cnt_s[NCHUNK][33];
  __shared__ int off_s[NCHUNK][33];
  const int tid = threadIdx.x;
  const int ch  = tid >> 5;
  const int ln  = (tid & 31) + 1;   // 1..32
  const int base = ch * CHSZ;
  int c = 0;
  for (int i = 0; i < CHSZ; ++i) c += (word_lens[base + i] == ln);
  cnt_s[ch][ln] = c;
  __syncthreads();
  if (tid == 0) {
    int run = 0;
    for (int l = 32; l >= 1; --l)
      for (int c2 = 0; c2 < NCHUNK; ++c2) { off_s[c2][l] = run; run += cnt_s[c2][l]; }
  }
  __syncthreads();
  int ptr = off_s[ch][ln];
  for (int i = 0; i < CHSZ; ++i) {
    int wi = base + i;
    if (word_lens[wi] == ln) perm[ptr++] = wi;
  }
}

// ---------------------------------------------------------------------------
// K2: MFMA BiLSTM recurrence. Block = 32 sorted words x 1 dir, 8 waves.
// Wave w owns gate-columns x in {2w, 2w+1}: nt = u*16 + x.
// acc[u][jj][mt] = 64 f32/thread (AGPR); hot-loop B addressing = 2 pointers
// + imm offsets (layout above) -> no address spill.
// C/D layout (verified m89): word = mt*16 + (lane>>4)*4 + reg, col = lane&15.
// ---------------------------------------------------------------------------
__global__ __launch_bounds__(512, 2) void k_lstm(
    const int* __restrict__ char_ids, const int* __restrict__ word_lens,
    const int* __restrict__ perm,
    const __hip_bfloat16* __restrict__ Bpack, unsigned short* __restrict__ hcat) {
  const int tid  = threadIdx.x;
  const int lane = tid & 63;
  const int w    = tid >> 6;       // wave 0..7
  const int w0   = blockIdx.x * M_;
  const int dir  = blockIdx.y;     // 0 fwd, 1 bwd

  __shared__ unsigned short hL[M_][KPAD];  // 24.5 KB
  __shared__ int ids_s[M_][L_];            // 4 KB
  __shared__ int len_s[M_];
  __shared__ int pw_s[M_];

  if (tid < M_) {
    int gw = perm[w0 + tid];
    pw_s[tid]  = gw;
    len_s[tid] = word_lens[gw];
  }
  __syncthreads();
  for (int i = tid; i < M_ * L_; i += 512) {
    int q = i >> 5;
    ids_s[q][i & 31] = char_ids[pw_s[q] * L_ + (i & 31)];
  }
  for (int i = tid; i < M_ * KPAD / 2; i += 512) ((unsigned int*)hL)[i] = 0u;
  __syncthreads();

  // one-hot for t=0
  if (tid < M_) {
    int len = len_s[tid];
    int tt  = dir ? (len - 1) : 0;
    hL[tid][H_ + ids_s[tid][tt]] = 0x3F80;  // bf16 1.0
  }
  int mlen = 0;
#pragma unroll 8
  for (int m = 0; m < M_; ++m) mlen = max(mlen, len_s[m]);
  unsigned lrp[2];
#pragma unroll
  for (int mt = 0; mt < 2; ++mt) {
    int bw = mt * 16 + ((lane >> 4) << 2);
    lrp[mt] = (unsigned)len_s[bw] | ((unsigned)len_s[bw + 1] << 8) |
              ((unsigned)len_s[bw + 2] << 16) | ((unsigned)len_s[bw + 3] << 24);
  }
  __syncthreads();

  // per-dir, per-wave base: Bpack[dir][ks=0][w][0][lane][0]
  const char* Bb0 = (const char*)Bpack + (size_t)dir * (KS_ * 8 * 8 * 64 * 16)
                    + (size_t)w * (8 * 64 * 16) + (size_t)lane * 16;
  const int   aoff = (lane >> 4) << 4;     // byte offset of this lane's 8 k-elems
  const char* ar0  = (const char*)&hL[ 0 + (lane & 15)][0];
  const char* ar1  = (const char*)&hL[16 + (lane & 15)][0];

  float c_[2][2][4];                       // [jj][mt][r]
#pragma unroll
  for (int jj = 0; jj < 2; ++jj)
#pragma unroll
    for (int mt = 0; mt < 2; ++mt)
#pragma unroll
      for (int r = 0; r < 4; ++r) c_[jj][mt][r] = 0.f;

  for (int t = 0; t < mlen; ++t) {
    f4v acc[4][2][2];                      // [gate u][jj][mt]
#pragma unroll
    for (int u = 0; u < 4; ++u)
#pragma unroll
      for (int jj = 0; jj < 2; ++jj)
#pragma unroll
        for (int mt = 0; mt < 2; ++mt) acc[u][jj][mt] = (f4v){0.f, 0.f, 0.f, 0.f};

    const char* bp0 = Bb0;            // fragments 0..3 (imm offs 0..3072)
    const char* bp1 = Bb0 + 4096;     // fragments 4..7
#pragma unroll 2
    for (int ks = 0; ks < KS_; ++ks) {
      s8v af0 = *(const s8v*)(ar0 + ks * 64 + aoff);
      s8v af1 = *(const s8v*)(ar1 + ks * 64 + aoff);
      s8v b0 = *(const s8v*)(bp0 + 0);
      s8v b1 = *(const s8v*)(bp0 + 1024);
      s8v b2 = *(const s8v*)(bp0 + 2048);
      s8v b3 = *(const s8v*)(bp0 + 3072);
      s8v b4 = *(const s8v*)(bp1 + 0);
      s8v b5 = *(const s8v*)(bp1 + 1024);
      s8v b6 = *(const s8v*)(bp1 + 2048);
      s8v b7 = *(const s8v*)(bp1 + 3072);
      // f = u*2 + jj
      acc[0][0][0] = __builtin_amdgcn_mfma_f32_16x16x32_bf16(af0, b0, acc[0][0][0], 0, 0, 0);
      acc[0][0][1] = __builtin_amdgcn_mfma_f32_16x16x32_bf16(af1, b0, acc[0][0][1], 0, 0, 0);
      acc[0][1][0] = __builtin_amdgcn_mfma_f32_16x16x32_bf16(af0, b1, acc[0][1][0], 0, 0, 0);
      acc[0][1][1] = __builtin_amdgcn_mfma_f32_16x16x32_bf16(af1, b1, acc[0][1][1], 0, 0, 0);
      acc[1][0][0] = __builtin_amdgcn_mfma_f32_16x16x32_bf16(af0, b2, acc[1][0][0], 0, 0, 0);
      acc[1][0][1] = __builtin_amdgcn_mfma_f32_16x16x32_bf16(af1, b2, acc[1][0][1], 0, 0, 0);
      acc[1][1][0] = __builtin_amdgcn_mfma_f32_16x16x32_bf16(af0, b3, acc[1][1][0], 0, 0, 0);
      acc[1][1][1] = __builtin_amdgcn_mfma_f32_16x16x32_bf16(af1, b3, acc[1][1][1], 0, 0, 0);
      acc[2][0][0] = __builtin_amdgcn_mfma_f32_16x16x32_bf16(af0, b4, acc[2][0][0], 0, 0, 0);
      acc[2][0][1] = __builtin_amdgcn_mfma_f32_16x16x32_bf16(af1, b4, acc[2][0][1], 0, 0, 0);
      acc[2][1][0] = __builtin_amdgcn_mfma_f32_16x16x32_bf16(af0, b5, acc[2][1][0], 0, 0, 0);
      acc[2][1][1] = __builtin_amdgcn_mfma_f32_16x16x32_bf16(af1, b5, acc[2][1][1], 0, 0, 0);
      acc[3][0][0] = __builtin_amdgcn_mfma_f32_16x16x32_bf16(af0, b6, acc[3][0][0], 0, 0, 0);
      acc[3][0][1] = __builtin_amdgcn_mfma_f32_16x16x32_bf16(af1, b6, acc[3][0][1], 0, 0, 0);
      acc[3][1][0] = __builtin_amdgcn_mfma_f32_16x16x32_bf16(af0, b7, acc[3][1][0], 0, 0, 0);
      acc[3][1][1] = __builtin_amdgcn_mfma_f32_16x16x32_bf16(af1, b7, acc[3][1][1], 0, 0, 0);
      bp0 += 8 * 8 * 64 * 16 / 8;   // 65536 / 8 waves? no: full ks stride below
      bp1 += 65536;
      bp0 += 65536 - 8 * 8 * 64 * 16 / 8;  // net +65536 (kept simple for compiler)
    }

    __syncthreads();   // all waves done reading hL for step t

    // elementwise gates + masked state update; write h_new (bf16) to LDS
#pragma unroll
    for (int jj = 0; jj < 2; ++jj) {
#pragma unroll
      for (int mt = 0; mt < 2; ++mt) {
#pragma unroll
        for (int r = 0; r < 4; ++r) {
          const int m = mt * 16 + ((lane >> 4) << 2) + r;
          const int p = (2 * w + jj) * 16 + (lane & 15);
          float gi = acc[0][jj][mt][r];
          float gf = acc[1][jj][mt][r];
          float gg = acc[2][jj][mt][r];
          float go = acc[3][jj][mt][r];
          float si = 1.f / (1.f + __expf(-gi));
          float sf = 1.f / (1.f + __expf(-gf));
          float so = 1.f / (1.f + __expf(-go));
          float tg = 2.f / (1.f + __expf(-2.f * gg)) - 1.f;
          float cn = sf * c_[jj][mt][r] + si * tg;
          float hn = so * (2.f / (1.f + __expf(-2.f * cn)) - 1.f);
          int len = (int)((lrp[mt] >> (8 * r)) & 255u);
          if (t < len) {
            c_[jj][mt][r] = cn;
            union { __hip_bfloat16 b; unsigned short u; } cv;
            cv.b = __float2bfloat16(hn);
            hL[m][p] = cv.u;
          }
        }
      }
    }
    // advance one-hot to step t+1
    if (tid < M_ && t + 1 < mlen) {
      int len  = len_s[tid];
      int told = dir ? max(len - 1 - t, 0)       : min(t, len - 1);
      int tnew = dir ? max(len - 1 - (t + 1), 0) : min(t + 1, len - 1);
      hL[tid][H_ + ids_s[tid][told]] = 0;
      hL[tid][H_ + ids_s[tid][tnew]] = 0x3F80;
    }
    __syncthreads();   // h(t+1) + one-hot(t+1) visible
  }

  // write frozen h (bf16) to hcat at ORIGINAL word position: [h_bwd | h_fwd]
  const int off = dir ? 0 : H_;
  for (int i = tid; i < M_ * H_; i += 512) {
    int q   = i >> 8;        // local word
    int pos = i & 255;
    hcat[(size_t)pw_s[q] * (2 * H_) + off + pos] = hL[q][pos];
  }
}

// ---------------------------------------------------------------------------
// K3: wemb = hcat(bf16) @ pW^T + pb;  also writes lens_out (= W) slots.
// ---------------------------------------------------------------------------
#define PM_ 16
__global__ __launch_bounds__(256) void k_proj(
    const unsigned short* __restrict__ hcat, const float* __restrict__ pW,
    const float* __restrict__ pb, float* __restrict__ out) {
  const int tid = threadIdx.x;
  const int n0  = blockIdx.x * PM_;
  __shared__ float hs[PM_][2 * H_];   // 32 KB
  for (int i = tid; i < PM_ * 2 * H_; i += 256) {
    unsigned int ui = ((unsigned int)hcat[(size_t)n0 * 2 * H_ + i]) << 16;
    ((float*)hs)[i] = __uint_as_float(ui);
  }
  __syncthreads();

  const float* pwr = pW + tid * (2 * H_);
  float acc[PM_];
#pragma unroll
  for (int m = 0; m < PM_; ++m) acc[m] = 0.f;

#pragma unroll 2
  for (int k = 0; k < 2 * H_; k += 4) {
    float4 w4 = *(const float4*)(pwr + k);
#pragma unroll
    for (int m = 0; m < PM_; ++m) {
      float4 h4 = *(const float4*)(&hs[m][k]);
      acc[m] += w4.x * h4.x + w4.y * h4.y + w4.z * h4.z + w4.w * h4.w;
    }
  }
  const float bias = pb[tid];
#pragma unroll
  for (int m = 0; m < PM_; ++m) out[(n0 + m) * H_ + tid] = acc[m] + bias;

  if (blockIdx.x == 0 && tid < B_) out[NW * H_ + tid] = (float)W_;
}

// ---------------------------------------------------------------------------
extern "C" void kernel_launch(void* const* d_in, const int* in_sizes, int n_in,
                              void* d_out, int out_size, void* d_ws, size_t ws_size,
                              hipStream_t stream) {
  const int*   char_ids  = (const int*)  d_in[0];
  const int*   word_lens = (const int*)  d_in[1];
  const float* emb       = (const float*)d_in[2];
  const float* Wih_f     = (const float*)d_in[3];
  const float* Whh_f     = (const float*)d_in[4];
  const float* bih_f     = (const float*)d_in[5];
  const float* bhh_f     = (const float*)d_in[6];
  const float* Wih_b     = (const float*)d_in[7];
  const float* Whh_b     = (const float*)d_in[8];
  const float* bih_b     = (const float*)d_in[9];
  const float* bhh_b     = (const float*)d_in[10];
  const float* pW        = (const float*)d_in[11];
  const float* pb        = (const float*)d_in[12];
  float* out = (float*)d_out;

  // ws layout: [Bpack 1.5MB][perm 32KB][eproj 1MB | hcat(bf16) 8.4MB]
  const size_t BPACK_BYTES = (size_t)2 * KS_ * 8 * 8 * 64 * 8 * 2;
  __hip_bfloat16* Bpack = (__hip_bfloat16*)d_ws;
  int*   perm  = (int*)((char*)d_ws + BPACK_BYTES);
  float* eproj = (float*)((char*)d_ws + BPACK_BYTES + NW * sizeof(int));
  unsigned short* hcat = (unsigned short*)eproj;  // eproj dead after k_pack

  k_sort<<<dim3(1), dim3(256), 0, stream>>>(word_lens, perm);
  k_embproj<<<dim3(2 * V_), dim3(256), 0, stream>>>(emb, Wih_f, bih_f, bhh_f,
                                                    Wih_b, bih_b, bhh_b, eproj);
  k_pack<<<dim3(2 * KS_ * 64), dim3(64), 0, stream>>>(eproj, Whh_f, Whh_b, Bpack);
  k_lstm<<<dim3(NW / M_, 2), dim3(512), 0, stream>>>(char_ids, word_lens, perm, Bpack, hcat);
  k_proj<<<dim3(NW / PM_), dim3(256), 0, stream>>>(hcat, pW, pb, out);
}

// Round 8
// 813.413 us; speedup vs baseline: 3.0565x; 1.0265x over previous
//
#include <hip/hip_runtime.h>
#include <hip/hip_bf16.h>
#include <math.h>

// Problem constants
#define B_  64
#define W_  128
#define L_  32
#define V_  128
#define E_  128
#define H_  256
#define G4_ 1024      // 4*H
#define NW  8192      // B*W words
#define KS_ 8         // MFMA k-steps: h only (K=256); eproj added via gather
#define KPAD 264      // padded LDS row (bf16): 256 used + 8 pad (528B = 33*16B, odd)
#define M_  32        // words per block

typedef short s8v  __attribute__((ext_vector_type(8)));  // 8 bf16 (4 VGPR)
typedef float f4v  __attribute__((ext_vector_type(4)));

// ---------------------------------------------------------------------------
// K1: ep4[dir][v][col][gate] = dot(emb[v], Wih_dir[gate*256+col]) + biases
// (gate-last f32x4 layout so k_lstm gathers i,f,g,o for one (word,col) in a
// single dwordx4 load)
// ---------------------------------------------------------------------------
__global__ __launch_bounds__(256) void k_embproj(
    const float* __restrict__ emb,
    const float* __restrict__ Wih_f, const float* __restrict__ bih_f, const float* __restrict__ bhh_f,
    const float* __restrict__ Wih_b, const float* __restrict__ bih_b, const float* __restrict__ bhh_b,
    float* __restrict__ ep4) {
  int v   = blockIdx.x & (V_ - 1);
  int dir = blockIdx.x >> 7;
  const float* Wih = dir ? Wih_b : Wih_f;
  const float* b1  = dir ? bih_b : bih_f;
  const float* b2  = dir ? bhh_b : bhh_f;
  __shared__ float es[E_];
  if (threadIdx.x < E_) es[threadIdx.x] = emb[v * E_ + threadIdx.x];
  __syncthreads();
#pragma unroll
  for (int q = 0; q < 4; ++q) {
    int g = q * 256 + threadIdx.x;       // g = gate*256 + col
    const float* wr = Wih + g * E_;
    float a = 0.f;
#pragma unroll 4
    for (int k = 0; k < E_; k += 4) {
      float4 w4 = *(const float4*)(wr + k);
      float4 e4 = *(const float4*)(es + k);
      a += w4.x * e4.x + w4.y * e4.y + w4.z * e4.z + w4.w * e4.w;
    }
    int gate = g >> 8, col = g & 255;
    ep4[(((dir * V_ + v) << 8) + col) * 4 + gate] = a + b1[g] + b2[g];
  }
}

// ---------------------------------------------------------------------------
// K1b: pack Whh^T (256 x 1024) per dir into per-WAVE-contiguous MFMA
// B-fragment layout:  Bpack[dir][ks][w][f][lane][8 elems]  (bf16)
//   f = u*2 + jj -> nt = u*16 + 2*w + jj
//   elem j: Bmat[k][n] = Whh[n][k], k = ks*32 + (lane>>4)*8 + j,
//                                   n = nt*16 + (lane&15)
// ---------------------------------------------------------------------------
__global__ __launch_bounds__(64) void k_pack(
    const float* __restrict__ Whh_f, const float* __restrict__ Whh_b,
    __hip_bfloat16* __restrict__ Bpack) {
  const int lane = threadIdx.x;
  const int f    = blockIdx.x & 7;
  const int w    = (blockIdx.x >> 3) & 7;
  const int ks   = (blockIdx.x >> 6) % KS_;
  const int dir  = blockIdx.x / (64 * KS_);
  const float* Whh = dir ? Whh_b : Whh_f;
  const int u  = f >> 1, jj = f & 1;
  const int nt = u * 16 + 2 * w + jj;
  const int n  = nt * 16 + (lane & 15);
  const int k0 = ks * 32 + (lane >> 4) * 8;
  size_t base = ((((size_t)(dir * KS_ + ks) * 8 + w) * 8 + f) * 64 + lane) * 8;
#pragma unroll
  for (int j = 0; j < 8; ++j)
    Bpack[base + j] = __float2bfloat16(Whh[n * H_ + k0 + j]);
}

// ---------------------------------------------------------------------------
// K1c: deterministic stable counting sort of words by length, DESCENDING.
// ---------------------------------------------------------------------------
#define NCHUNK 8
#define CHSZ  (NW / NCHUNK)
__global__ __launch_bounds__(256) void k_sort(const int* __restrict__ word_lens,
                                              int* __restrict__ perm) {
  __shared__ int cnt_s[NCHUNK][33];
  __shared__ int off_s[NCHUNK][33];
  const int tid = threadIdx.x;
  const int ch  = tid >> 5;
  const int ln  = (tid & 31) + 1;   // 1..32
  const int base = ch * CHSZ;
  int c = 0;
  for (int i = 0; i < CHSZ; ++i) c += (word_lens[base + i] == ln);
  cnt_s[ch][ln] = c;
  __syncthreads();
  if (tid == 0) {
    int run = 0;
    for (int l = 32; l >= 1; --l)
      for (int c2 = 0; c2 < NCHUNK; ++c2) { off_s[c2][l] = run; run += cnt_s[c2][l]; }
  }
  __syncthreads();
  int ptr = off_s[ch][ln];
  for (int i = 0; i < CHSZ; ++i) {
    int wi = base + i;
    if (word_lens[wi] == ln) perm[ptr++] = wi;
  }
}

// ---------------------------------------------------------------------------
// K2: MFMA BiLSTM recurrence. 1-D grid of 512 blocks; LPT pairing:
// bid<256 -> task bid, else task 767-bid, so under round-robin placement
// CU c co-hosts task c (long words) + task 511-c (short words).
// Task s: chunk = s>>1 (32 sorted words), dir = s&1.
// Wave w owns gate-cols {2w,2w+1}; acc = 64 f32/thread (AGPR).
// eproj contribution gathered per-step from ep4 (f32x4, 16-lane coalesced).
// C/D layout (verified m89): word = mt*16 + (lane>>4)*4 + reg, col = lane&15.
// ---------------------------------------------------------------------------
__global__ __launch_bounds__(512, 2) void k_lstm(
    const int* __restrict__ char_ids, const int* __restrict__ word_lens,
    const int* __restrict__ perm, const float* __restrict__ ep4,
    const __hip_bfloat16* __restrict__ Bpack, unsigned short* __restrict__ hcat) {
  const int tid  = threadIdx.x;
  const int lane = tid & 63;
  const int w    = tid >> 6;       // wave 0..7
  const int bid  = blockIdx.x;
  const int s    = (bid < 256) ? bid : 767 - bid;
  const int dir  = s & 1;
  const int w0   = (s >> 1) * M_;

  __shared__ unsigned short hL[M_][KPAD];  // 16.5 KB (h only)
  __shared__ int ids_s[M_][L_ + 1];        // 4.2 KB (pad -> bank spread)
  __shared__ int len_s[M_];
  __shared__ int pw_s[M_];

  if (tid < M_) {
    int gw = perm[w0 + tid];
    pw_s[tid]  = gw;
    len_s[tid] = word_lens[gw];
  }
  __syncthreads();
  for (int i = tid; i < M_ * L_; i += 512) {
    int q = i >> 5;
    ids_s[q][i & 31] = char_ids[pw_s[q] * L_ + (i & 31)];
  }
  for (int i = tid; i < M_ * KPAD / 2; i += 512) ((unsigned int*)hL)[i] = 0u;
  __syncthreads();

  int mlen = 0;
#pragma unroll 8
  for (int m = 0; m < M_; ++m) mlen = max(mlen, len_s[m]);
  unsigned lrp[2];
#pragma unroll
  for (int mt = 0; mt < 2; ++mt) {
    int bw = mt * 16 + ((lane >> 4) << 2);
    lrp[mt] = (unsigned)len_s[bw] | ((unsigned)len_s[bw + 1] << 8) |
              ((unsigned)len_s[bw + 2] << 16) | ((unsigned)len_s[bw + 3] << 24);
  }

  // per-dir, per-wave base: Bpack[dir][ks=0][w][0][lane][0]
  const char* Bb0 = (const char*)Bpack + (size_t)dir * (KS_ * 8 * 8 * 64 * 16)
                    + (size_t)w * (8 * 64 * 16) + (size_t)lane * 16;
  const int   aoff = (lane >> 4) << 4;     // byte offset of lane's 8 k-elems
  const char* ar0  = (const char*)&hL[ 0 + (lane & 15)][0];
  const char* ar1  = (const char*)&hL[16 + (lane & 15)][0];
  const f4v*  epv  = (const f4v*)ep4 + ((size_t)dir << 15);  // dir*V*256
  const int   p0   = 2 * w * 16 + (lane & 15);               // col of jj=0
  const int   g4   = (lane >> 4) << 2;

  float c_[2][2][4];                       // [jj][mt][r]
#pragma unroll
  for (int jj = 0; jj < 2; ++jj)
#pragma unroll
    for (int mt = 0; mt < 2; ++mt)
#pragma unroll
      for (int r = 0; r < 4; ++r) c_[jj][mt][r] = 0.f;

  for (int t = 0; t < mlen; ++t) {
    f4v acc[4][2][2];                      // [gate u][jj][mt]
#pragma unroll
    for (int u = 0; u < 4; ++u)
#pragma unroll
      for (int jj = 0; jj < 2; ++jj)
#pragma unroll
        for (int mt = 0; mt < 2; ++mt) acc[u][jj][mt] = (f4v){0.f, 0.f, 0.f, 0.f};

    const char* bp0 = Bb0;            // fragments 0..3 (imm offs 0..3072)
    const char* bp1 = Bb0 + 4096;     // fragments 4..7
#pragma unroll 2
    for (int ks = 0; ks < KS_; ++ks) {
      s8v af0 = *(const s8v*)(ar0 + ks * 64 + aoff);
      s8v af1 = *(const s8v*)(ar1 + ks * 64 + aoff);
      s8v b0 = *(const s8v*)(bp0 + 0);
      s8v b1 = *(const s8v*)(bp0 + 1024);
      s8v b2 = *(const s8v*)(bp0 + 2048);
      s8v b3 = *(const s8v*)(bp0 + 3072);
      s8v b4 = *(const s8v*)(bp1 + 0);
      s8v b5 = *(const s8v*)(bp1 + 1024);
      s8v b6 = *(const s8v*)(bp1 + 2048);
      s8v b7 = *(const s8v*)(bp1 + 3072);
      acc[0][0][0] = __builtin_amdgcn_mfma_f32_16x16x32_bf16(af0, b0, acc[0][0][0], 0, 0, 0);
      acc[0][0][1] = __builtin_amdgcn_mfma_f32_16x16x32_bf16(af1, b0, acc[0][0][1], 0, 0, 0);
      acc[0][1][0] = __builtin_amdgcn_mfma_f32_16x16x32_bf16(af0, b1, acc[0][1][0], 0, 0, 0);
      acc[0][1][1] = __builtin_amdgcn_mfma_f32_16x16x32_bf16(af1, b1, acc[0][1][1], 0, 0, 0);
      acc[1][0][0] = __builtin_amdgcn_mfma_f32_16x16x32_bf16(af0, b2, acc[1][0][0], 0, 0, 0);
      acc[1][0][1] = __builtin_amdgcn_mfma_f32_16x16x32_bf16(af1, b2, acc[1][0][1], 0, 0, 0);
      acc[1][1][0] = __builtin_amdgcn_mfma_f32_16x16x32_bf16(af0, b3, acc[1][1][0], 0, 0, 0);
      acc[1][1][1] = __builtin_amdgcn_mfma_f32_16x16x32_bf16(af1, b3, acc[1][1][1], 0, 0, 0);
      acc[2][0][0] = __builtin_amdgcn_mfma_f32_16x16x32_bf16(af0, b4, acc[2][0][0], 0, 0, 0);
      acc[2][0][1] = __builtin_amdgcn_mfma_f32_16x16x32_bf16(af1, b4, acc[2][0][1], 0, 0, 0);
      acc[2][1][0] = __builtin_amdgcn_mfma_f32_16x16x32_bf16(af0, b5, acc[2][1][0], 0, 0, 0);
      acc[2][1][1] = __builtin_amdgcn_mfma_f32_16x16x32_bf16(af1, b5, acc[2][1][1], 0, 0, 0);
      acc[3][0][0] = __builtin_amdgcn_mfma_f32_16x16x32_bf16(af0, b6, acc[3][0][0], 0, 0, 0);
      acc[3][0][1] = __builtin_amdgcn_mfma_f32_16x16x32_bf16(af1, b6, acc[3][0][1], 0, 0, 0);
      acc[3][1][0] = __builtin_amdgcn_mfma_f32_16x16x32_bf16(af0, b7, acc[3][1][0], 0, 0, 0);
      acc[3][1][1] = __builtin_amdgcn_mfma_f32_16x16x32_bf16(af1, b7, acc[3][1][1], 0, 0, 0);
      bp0 += 65536;   // ks stride = 8w * 8f * 64lanes * 16B
      bp1 += 65536;
    }

    __syncthreads();   // all waves done reading hL for step t

    // elementwise: gather xw = ep4[id(word,t)][col][4], gates, state update
#pragma unroll
    for (int mt = 0; mt < 2; ++mt) {
      const int mbase = mt * 16 + g4;
      f4v xw0[4], xw1[4];
#pragma unroll
      for (int r = 0; r < 4; ++r) {
        int len = (int)((lrp[mt] >> (8 * r)) & 255u);
        int tt  = dir ? max(len - 1 - t, 0) : t;      // t<32 always in-bounds
        int id  = ids_s[mbase + r][tt];
        const f4v* ep = epv + ((size_t)id << 8);
        xw0[r] = ep[p0];
        xw1[r] = ep[p0 + 16];
      }
#pragma unroll
      for (int jj = 0; jj < 2; ++jj) {
#pragma unroll
        for (int r = 0; r < 4; ++r) {
          const f4v xw = jj ? xw1[r] : xw0[r];
          const int m = mbase + r;
          const int p = (2 * w + jj) * 16 + (lane & 15);
          float gi = acc[0][jj][mt][r] + xw[0];
          float gf = acc[1][jj][mt][r] + xw[1];
          float gg = acc[2][jj][mt][r] + xw[2];
          float go = acc[3][jj][mt][r] + xw[3];
          float si = 1.f / (1.f + __expf(-gi));
          float sf = 1.f / (1.f + __expf(-gf));
          float so = 1.f / (1.f + __expf(-go));
          float tg = 2.f / (1.f + __expf(-2.f * gg)) - 1.f;
          float cn = sf * c_[jj][mt][r] + si * tg;
          float hn = so * (2.f / (1.f + __expf(-2.f * cn)) - 1.f);
          int len = (int)((lrp[mt] >> (8 * r)) & 255u);
          if (t < len) {
            c_[jj][mt][r] = cn;
            union { __hip_bfloat16 b; unsigned short u; } cv;
            cv.b = __float2bfloat16(hn);
            hL[m][p] = cv.u;
          }
        }
      }
    }
    __syncthreads();   // h(t+1) visible before next MFMA phase
  }

  // write frozen h (bf16) to hcat at ORIGINAL word position: [h_bwd | h_fwd]
  const int off = dir ? 0 : H_;
  for (int i = tid; i < M_ * H_; i += 512) {
    int q   = i >> 8;        // local word
    int pos = i & 255;
    hcat[(size_t)pw_s[q] * (2 * H_) + off + pos] = hL[q][pos];
  }
}

// ---------------------------------------------------------------------------
// K3: wemb = hcat(bf16) @ pW^T + pb;  also writes lens_out (= W) slots.
// ---------------------------------------------------------------------------
#define PM_ 16
__global__ __launch_bounds__(256) void k_proj(
    const unsigned short* __restrict__ hcat, const float* __restrict__ pW,
    const float* __restrict__ pb, float* __restrict__ out) {
  const int tid = threadIdx.x;
  const int n0  = blockIdx.x * PM_;
  __shared__ float hs[PM_][2 * H_];   // 32 KB
  for (int i = tid; i < PM_ * 2 * H_; i += 256) {
    unsigned int ui = ((unsigned int)hcat[(size_t)n0 * 2 * H_ + i]) << 16;
    ((float*)hs)[i] = __uint_as_float(ui);
  }
  __syncthreads();

  const float* pwr = pW + tid * (2 * H_);
  float acc[PM_];
#pragma unroll
  for (int m = 0; m < PM_; ++m) acc[m] = 0.f;

#pragma unroll 2
  for (int k = 0; k < 2 * H_; k += 4) {
    float4 w4 = *(const float4*)(pwr + k);
#pragma unroll
    for (int m = 0; m < PM_; ++m) {
      float4 h4 = *(const float4*)(&hs[m][k]);
      acc[m] += w4.x * h4.x + w4.y * h4.y + w4.z * h4.z + w4.w * h4.w;
    }
  }
  const float bias = pb[tid];
#pragma unroll
  for (int m = 0; m < PM_; ++m) out[(n0 + m) * H_ + tid] = acc[m] + bias;

  if (blockIdx.x == 0 && tid < B_) out[NW * H_ + tid] = (float)W_;
}

// ---------------------------------------------------------------------------
extern "C" void kernel_launch(void* const* d_in, const int* in_sizes, int n_in,
                              void* d_out, int out_size, void* d_ws, size_t ws_size,
                              hipStream_t stream) {
  const int*   char_ids  = (const int*)  d_in[0];
  const int*   word_lens = (const int*)  d_in[1];
  const float* emb       = (const float*)d_in[2];
  const float* Wih_f     = (const float*)d_in[3];
  const float* Whh_f     = (const float*)d_in[4];
  const float* bih_f     = (const float*)d_in[5];
  const float* bhh_f     = (const float*)d_in[6];
  const float* Wih_b     = (const float*)d_in[7];
  const float* Whh_b     = (const float*)d_in[8];
  const float* bih_b     = (const float*)d_in[9];
  const float* bhh_b     = (const float*)d_in[10];
  const float* pW        = (const float*)d_in[11];
  const float* pb        = (const float*)d_in[12];
  float* out = (float*)d_out;

  // ws layout: [Bpack 1MB][ep4 1MB][perm 32KB][hcat(bf16) 8.4MB]
  const size_t BPACK_BYTES = (size_t)2 * KS_ * 8 * 8 * 64 * 8 * 2;   // 1 MB
  const size_t EP4_BYTES   = (size_t)2 * V_ * 256 * 4 * 4;           // 1 MB
  __hip_bfloat16* Bpack = (__hip_bfloat16*)d_ws;
  float* ep4  = (float*)((char*)d_ws + BPACK_BYTES);
  int*   perm = (int*)((char*)d_ws + BPACK_BYTES + EP4_BYTES);
  unsigned short* hcat = (unsigned short*)((char*)d_ws + BPACK_BYTES + EP4_BYTES + NW * sizeof(int));

  k_sort<<<dim3(1), dim3(256), 0, stream>>>(word_lens, perm);
  k_embproj<<<dim3(2 * V_), dim3(256), 0, stream>>>(emb, Wih_f, bih_f, bhh_f,
                                                    Wih_b, bih_b, bhh_b, ep4);
  k_pack<<<dim3(2 * KS_ * 64), dim3(64), 0, stream>>>(Whh_f, Whh_b, Bpack);
  k_lstm<<<dim3(512), dim3(512), 0, stream>>>(char_ids, word_lens, perm, ep4, Bpack, hcat);
  k_proj<<<dim3(NW / PM_), dim3(256), 0, stream>>>(hcat, pW, pb, out);
}